// Round 3
// baseline (18444.011 us; speedup 1.0000x reference)
//
#include <hip/hip_runtime.h>
#include <hip/hip_bf16.h>
#include <math.h>

// ---------------- problem constants ----------------
#define B_        4096
#define ENC_STEPS 49     // SRC-1
#define TGT_      25
#define R_        1024
#define H_        67
#define I_        82
#define IP_       96     // input padded to multiple of 32
#define IP2_      192    // split-bf16 (hi|lo) doubled K
#define NG_       3072   // 3*R
#define FCN_      128    // fc output padded 67 -> 128
#define K2_       2048   // 2*R

typedef unsigned short u16;
typedef __attribute__((ext_vector_type(8))) short bf16x8_t;
typedef __attribute__((ext_vector_type(4))) float f32x4_t;

// ---------------- helpers ----------------
__device__ __forceinline__ float bf2f(u16 h) {
    union { unsigned int u; float f; } v; v.u = ((unsigned int)h) << 16; return v.f;
}
__device__ __forceinline__ u16 f2bf(float f) {
    union { unsigned int u; float f; } v; v.f = f;
    unsigned int u = v.u;
    u += 0x7fffu + ((u >> 16) & 1u);   // RNE
    return (u16)(u >> 16);
}
__device__ __forceinline__ float sigmf(float x) { return 1.f / (1.f + __expf(-x)); }
__device__ __forceinline__ float tanhfast(float x) { return 1.f - 2.f / (__expf(2.f * x) + 1.f); }

// ---------------- weight prep ----------------
__global__ void cast_bf16_kernel(const float* __restrict__ s, u16* __restrict__ d, int n) {
    int i = blockIdx.x * 256 + threadIdx.x;
    if (i < n) d[i] = f2bf(s[i]);
}
// Wi1 [3072,82] -> [3072,192] bf16: cols 0..95 padded Wi1, cols 96..191 duplicate (hi|lo split)
__global__ void pad_wi1_dup_kernel(const float* __restrict__ s, u16* __restrict__ d) {
    int i = blockIdx.x * 256 + threadIdx.x;
    if (i >= NG_ * IP2_) return;
    int r = i / IP2_, c = i % IP2_;
    int cc = (c < IP_) ? c : c - IP_;
    d[i] = (cc < I_) ? f2bf(s[r * I_ + cc]) : (u16)0;
}
// Wfc [67,2048] -> [128,2048] bf16, zero-padded N rows
__global__ void pad_wfc_kernel(const float* __restrict__ s, u16* __restrict__ d) {
    int i = blockIdx.x * 256 + threadIdx.x;
    if (i >= FCN_ * K2_) return;
    int r = i / K2_, c = i % K2_;
    d[i] = (r < H_) ? f2bf(s[r * K2_ + c]) : (u16)0;
}

// all encoder inputs -> xall bf16 [ENC][B][192] (hi|lo split), one launch
__global__ void pad_all_x_kernel(const float* __restrict__ enc, u16* __restrict__ xall) {
    int i = blockIdx.x * 256 + threadIdx.x;
    if (i >= B_ * ENC_STEPS * IP_) return;
    int c = i % IP_;
    int t = (i / IP_) % ENC_STEPS;
    int b = i / (IP_ * ENC_STEPS);
    float v = (c < I_) ? enc[((size_t)b * ENC_STEPS + t) * I_ + c] : 0.f;
    u16 hi = f2bf(v);
    u16 lo = f2bf(v - bf2f(hi));
    size_t base = ((size_t)t * B_ + b) * IP2_;
    xall[base + c]       = hi;
    xall[base + IP_ + c] = lo;
}

// decoder inp for t==0 (later steps are fused into fc_finish)
__global__ void build_inp_kernel(const float* __restrict__ prev, int pstride,
                                 const float* __restrict__ dec, int t,
                                 u16* __restrict__ xpad) {
    int i = blockIdx.x * 256 + threadIdx.x;
    if (i >= B_ * IP_) return;
    int b = i / IP_, c = i % IP_;
    float v = 0.f;
    if (c < H_)      v = prev[(size_t)b * pstride + c];
    else if (c < I_) v = dec[((size_t)b * TGT_ + t) * I_ + c];
    u16 hi = f2bf(v);
    u16 lo = f2bf(v - bf2f(hi));
    xpad[(size_t)b * IP2_ + c]       = hi;
    xpad[(size_t)b * IP2_ + IP_ + c] = lo;
}

// ---------------- fused GRU step (one layer) ----------------
// Tile: 128 batch rows x 64 R-cols x 3 gates; 4 waves (2M x 2N), wave = 64x32x3.
// DIRECT-TO-REGISTER design: no LDS, no barriers. Each MFMA fragment
// (row = base + lane&15, k = (lane>>4)*8) is loaded straight from global as one
// b128 per lane; a fragment covers 16 rows x 64 aligned bytes -> zero L2 line
// amplification. Depth-1 register ping-pong (static names) gives the compiler a
// full MFMA cluster of slack per load group; compiler-inserted counted vmcnt
// waits provide the T4 "never drain to 0" discipline with no barriers at all.
template<int KX>
__global__ __launch_bounds__(256, 2) void gru_step_kernel(
    const u16* __restrict__ Ax, int ldax,       // [B, ldax] bf16 input
    const u16* __restrict__ Wx,                 // [3R, KX] bf16
    const u16* __restrict__ Ah, int ldah,       // [B, ldah] bf16 state (cur)
    const u16* __restrict__ Wh,                 // [3R, 1024] bf16
    const float* __restrict__ bi, const float* __restrict__ bh,
    float* __restrict__ hf,                     // [B, R] fp32 state, in/out (in-place per-tile)
    u16* __restrict__ hout)                     // bf16 state out (nxt buffer), row stride K2_
{
    const int tid  = threadIdx.x;
    const int lane = tid & 63, wave = tid >> 6;
    const int wm = wave >> 1, wn = wave & 1;          // 2x2 waves: WM=64, WN=32
    const int mbase = blockIdx.y * 128;
    const int nbase = blockIdx.x * 64;
    const int lr = lane & 15, lk = (lane >> 4) * 8;

    constexpr int NX = KX / 32;          // x-pass K-steps (even: 6 or 32)
    constexpr int NH = R_ / 32;          // h-pass K-steps (32)

    f32x4_t acc_r[4][2], acc_z[4][2], acc_xn[4][2], acc_hn[4][2];
#pragma unroll
    for (int i = 0; i < 4; i++)
#pragma unroll
        for (int j = 0; j < 2; j++) {
            acc_r[i][j]  = (f32x4_t){0,0,0,0};
            acc_z[i][j]  = (f32x4_t){0,0,0,0};
            acc_xn[i][j] = (f32x4_t){0,0,0,0};
            acc_hn[i][j] = (f32x4_t){0,0,0,0};
        }

    // one GEMM pass (nsteps of K=32) accumulating r/z and the given n-accumulator
    auto run_pass = [&](const u16* A, int lda, const u16* W, int ldw, int nsteps,
                        f32x4_t (&accn)[4][2]) {
        const u16* ap[4];
        const u16* wp[6];
#pragma unroll
        for (int i = 0; i < 4; i++)
            ap[i] = A + (size_t)(mbase + wm * 64 + i * 16 + lr) * lda + lk;
#pragma unroll
        for (int g = 0; g < 3; g++)
#pragma unroll
            for (int j = 0; j < 2; j++)
                wp[g * 2 + j] = W + ((size_t)g * R_ + nbase + wn * 32 + j * 16 + lr) * ldw + lk;

        bf16x8_t a0[4], w0[6], a1[4], w1[6];
        auto ld0 = [&](int k0) {
#pragma unroll
            for (int i = 0; i < 4; i++) a0[i] = *(const bf16x8_t*)(ap[i] + k0);
#pragma unroll
            for (int i = 0; i < 6; i++) w0[i] = *(const bf16x8_t*)(wp[i] + k0);
        };
        auto ld1 = [&](int k0) {
#pragma unroll
            for (int i = 0; i < 4; i++) a1[i] = *(const bf16x8_t*)(ap[i] + k0);
#pragma unroll
            for (int i = 0; i < 6; i++) w1[i] = *(const bf16x8_t*)(wp[i] + k0);
        };
        auto fm0 = [&]() {
            __builtin_amdgcn_s_setprio(1);
#pragma unroll
            for (int i = 0; i < 4; i++)
#pragma unroll
                for (int j = 0; j < 2; j++) {
                    acc_r[i][j] = __builtin_amdgcn_mfma_f32_16x16x32_bf16(a0[i], w0[j],     acc_r[i][j], 0, 0, 0);
                    acc_z[i][j] = __builtin_amdgcn_mfma_f32_16x16x32_bf16(a0[i], w0[2 + j], acc_z[i][j], 0, 0, 0);
                    accn[i][j]  = __builtin_amdgcn_mfma_f32_16x16x32_bf16(a0[i], w0[4 + j], accn[i][j], 0, 0, 0);
                }
            __builtin_amdgcn_s_setprio(0);
        };
        auto fm1 = [&]() {
            __builtin_amdgcn_s_setprio(1);
#pragma unroll
            for (int i = 0; i < 4; i++)
#pragma unroll
                for (int j = 0; j < 2; j++) {
                    acc_r[i][j] = __builtin_amdgcn_mfma_f32_16x16x32_bf16(a1[i], w1[j],     acc_r[i][j], 0, 0, 0);
                    acc_z[i][j] = __builtin_amdgcn_mfma_f32_16x16x32_bf16(a1[i], w1[2 + j], acc_z[i][j], 0, 0, 0);
                    accn[i][j]  = __builtin_amdgcn_mfma_f32_16x16x32_bf16(a1[i], w1[4 + j], accn[i][j], 0, 0, 0);
                }
            __builtin_amdgcn_s_setprio(0);
        };

        ld0(0);
#pragma unroll 1
        for (int s = 0; s < nsteps; s += 2) {
            if (s + 1 < nsteps) ld1((s + 1) * 32);   // prefetch next step
            fm0();                                    // compute current (waits only its own group)
            if (s + 2 < nsteps) ld0((s + 2) * 32);
            if (s + 1 < nsteps) fm1();
        }
    };

    run_pass(Ax, ldax, Wx, KX, NX, acc_xn);   // x @ Wx^T
    run_pass(Ah, ldah, Wh, R_, NH, acc_hn);   // h @ Wh^T

    // ---- epilogue: gates + state update ----
    // C/D layout: col = lane&15, row = (lane>>4)*4 + reg   [HW-verified]
    const int rr2 = (lane >> 4) * 4;
#pragma unroll
    for (int j = 0; j < 2; j++) {
        const int col = nbase + wn * 32 + j * 16 + lr;
        const float b_ir = bi[col],          b_hr = bh[col];
        const float b_iz = bi[R_ + col],     b_hz = bh[R_ + col];
        const float b_in = bi[2 * R_ + col], b_hn = bh[2 * R_ + col];
#pragma unroll
        for (int i = 0; i < 4; i++) {
#pragma unroll
            for (int r = 0; r < 4; r++) {
                const int row = mbase + wm * 64 + i * 16 + rr2 + r;
                const float hold = hf[(size_t)row * R_ + col];
                const float rv = sigmf(acc_r[i][j][r] + b_ir + b_hr);
                const float zv = sigmf(acc_z[i][j][r] + b_iz + b_hz);
                const float nv = tanhfast(acc_xn[i][j][r] + b_in + rv * (acc_hn[i][j][r] + b_hn));
                const float hn = (1.f - zv) * nv + zv * hold;
                hf[(size_t)row * R_ + col] = hn;
                hout[(size_t)row * K2_ + col] = f2bf(hn);
            }
        }
    }
}

// ---------------- FC: 4-way K-split partial GEMM (direct-to-register) ----------------
// part[kc][B][128] = s12[:, kc*512:(kc+1)*512] @ Wfc[:, same]^T
__global__ __launch_bounds__(256) void fc_part_kernel(
    const u16* __restrict__ A, const u16* __restrict__ W, float* __restrict__ part) {
    const int tid  = threadIdx.x;
    const int lane = tid & 63, wave = tid >> 6;
    const int wm = wave >> 1, wn = wave & 1;      // WM=32, WN=64
    const int mbase = blockIdx.y * 64;
    const int kbase = blockIdx.x * 512;
    const int lr = lane & 15, lk = (lane >> 4) * 8;

    f32x4_t acc[2][4];
#pragma unroll
    for (int i = 0; i < 2; i++)
#pragma unroll
        for (int j = 0; j < 4; j++) acc[i][j] = (f32x4_t){0, 0, 0, 0};

    const u16* ap[2];
    const u16* bp[4];
#pragma unroll
    for (int i = 0; i < 2; i++)
        ap[i] = A + (size_t)(mbase + wm * 32 + i * 16 + lr) * K2_ + kbase + lk;
#pragma unroll
    for (int j = 0; j < 4; j++)
        bp[j] = W + (size_t)(wn * 64 + j * 16 + lr) * K2_ + kbase + lk;

    bf16x8_t a0[2], b0[4], a1[2], b1[4];
    auto ld0 = [&](int k0) {
#pragma unroll
        for (int i = 0; i < 2; i++) a0[i] = *(const bf16x8_t*)(ap[i] + k0);
#pragma unroll
        for (int j = 0; j < 4; j++) b0[j] = *(const bf16x8_t*)(bp[j] + k0);
    };
    auto ld1 = [&](int k0) {
#pragma unroll
        for (int i = 0; i < 2; i++) a1[i] = *(const bf16x8_t*)(ap[i] + k0);
#pragma unroll
        for (int j = 0; j < 4; j++) b1[j] = *(const bf16x8_t*)(bp[j] + k0);
    };
    auto fm0 = [&]() {
#pragma unroll
        for (int i = 0; i < 2; i++)
#pragma unroll
            for (int j = 0; j < 4; j++)
                acc[i][j] = __builtin_amdgcn_mfma_f32_16x16x32_bf16(a0[i], b0[j], acc[i][j], 0, 0, 0);
    };
    auto fm1 = [&]() {
#pragma unroll
        for (int i = 0; i < 2; i++)
#pragma unroll
            for (int j = 0; j < 4; j++)
                acc[i][j] = __builtin_amdgcn_mfma_f32_16x16x32_bf16(a1[i], b1[j], acc[i][j], 0, 0, 0);
    };

    ld0(0);
#pragma unroll 1
    for (int s = 0; s < 16; s += 2) {
        if (s + 1 < 16) ld1((s + 1) * 32);
        fm0();
        if (s + 2 < 16) ld0((s + 2) * 32);
        if (s + 1 < 16) fm1();
    }

    const int rr2 = (lane >> 4) * 4;
#pragma unroll
    for (int i = 0; i < 2; i++)
#pragma unroll
        for (int r = 0; r < 4; r++) {
            int row = mbase + wm * 32 + i * 16 + rr2 + r;
#pragma unroll
            for (int j = 0; j < 4; j++) {
                int col = wn * 64 + j * 16 + lr;
                part[((size_t)blockIdx.x * B_ + row) * FCN_ + col] = acc[i][j][r];
            }
        }
}

// out[:, t, :] = prev + sum(4 partials)[:, :67] + bfc  (deterministic reduce)
// FUSED: also builds xpad2 (hi|lo bf16) for decoder step t+1 when write_x != 0.
__global__ void fc_finish_kernel(const float* __restrict__ part, const float* __restrict__ prev,
                                 int pstride, const float* __restrict__ bfc,
                                 float* __restrict__ out, int t,
                                 const float* __restrict__ dec, u16* __restrict__ xpad,
                                 int write_x) {
    int i = blockIdx.x * 256 + threadIdx.x;
    if (i >= B_ * IP_) return;
    int b = i / IP_, c = i % IP_;
    float v = 0.f;
    if (c < H_) {
        size_t idx = (size_t)b * FCN_ + c;
        const size_t S = (size_t)B_ * FCN_;
        float s = (part[idx] + part[S + idx]) + (part[2 * S + idx] + part[3 * S + idx]);
        v = prev[(size_t)b * pstride + c] + s + bfc[c];
        out[((size_t)b * TGT_ + t) * H_ + c] = v;
    } else if (c < I_ && write_x) {
        v = dec[((size_t)b * TGT_ + (t + 1)) * I_ + c];   // next step's action channels
    }
    if (write_x) {
        u16 hi = f2bf(v);
        u16 lo = f2bf(v - bf2f(hi));
        xpad[(size_t)b * IP2_ + c]       = hi;
        xpad[(size_t)b * IP2_ + IP_ + c] = lo;
    }
}

// ---------------- host launcher ----------------
extern "C" void kernel_launch(void* const* d_in, const int* in_sizes, int n_in,
                              void* d_out, int out_size, void* d_ws, size_t ws_size,
                              hipStream_t stream) {
    (void)in_sizes; (void)n_in; (void)out_size; (void)ws_size;
    const float* enc = (const float*)d_in[0];
    const float* dec = (const float*)d_in[1];
    const float* Wi1 = (const float*)d_in[2];
    const float* Wh1 = (const float*)d_in[3];
    const float* bi1 = (const float*)d_in[4];
    const float* bh1 = (const float*)d_in[5];
    const float* Wi2 = (const float*)d_in[6];
    const float* Wh2 = (const float*)d_in[7];
    const float* bi2 = (const float*)d_in[8];
    const float* bh2 = (const float*)d_in[9];
    const float* Wfc = (const float*)d_in[10];
    const float* bfc = (const float*)d_in[11];
    float* out = (float*)d_out;

    char* ws = (char*)d_ws;
    size_t off = 0;
    auto alloc = [&](size_t bytes) -> char* {
        char* p = ws + off;
        off += (bytes + 255) & ~(size_t)255;
        return p;
    };
    u16* Wh1b  = (u16*)alloc((size_t)NG_ * R_ * 2);
    u16* Wi2b  = (u16*)alloc((size_t)NG_ * R_ * 2);
    u16* Wh2b  = (u16*)alloc((size_t)NG_ * R_ * 2);
    u16* Wi1pb = (u16*)alloc((size_t)NG_ * IP2_ * 2);
    u16* Wfcb  = (u16*)alloc((size_t)FCN_ * K2_ * 2);
    // contiguous zero-init group: sbuf0, s1f, s2f
    u16* sbuf0 = (u16*)alloc((size_t)B_ * K2_ * 2);
    float* s1f = (float*)alloc((size_t)B_ * R_ * 4);
    float* s2f = (float*)alloc((size_t)B_ * R_ * 4);
    u16* sbuf1 = (u16*)alloc((size_t)B_ * K2_ * 2);
    u16* xall  = (u16*)alloc((size_t)ENC_STEPS * B_ * IP2_ * 2);
    u16* xpad2 = (u16*)alloc((size_t)B_ * IP2_ * 2);
    float* cfcp = (float*)alloc((size_t)4 * B_ * FCN_ * 4);
    u16* sbuf[2] = { sbuf0, sbuf1 };

    hipMemsetAsync(sbuf0, 0,
                   (size_t)B_ * K2_ * 2 + 2 * (size_t)B_ * R_ * 4, stream);

    // weight prep (rerun every call: ws re-poisoned)
    cast_bf16_kernel<<<(NG_ * R_ + 255) / 256, 256, 0, stream>>>(Wh1, Wh1b, NG_ * R_);
    cast_bf16_kernel<<<(NG_ * R_ + 255) / 256, 256, 0, stream>>>(Wi2, Wi2b, NG_ * R_);
    cast_bf16_kernel<<<(NG_ * R_ + 255) / 256, 256, 0, stream>>>(Wh2, Wh2b, NG_ * R_);
    pad_wi1_dup_kernel<<<(NG_ * IP2_ + 255) / 256, 256, 0, stream>>>(Wi1, Wi1pb);
    pad_wfc_kernel<<<(FCN_ * K2_ + 255) / 256, 256, 0, stream>>>(Wfc, Wfcb);
    pad_all_x_kernel<<<(B_ * ENC_STEPS * IP_ + 255) / 256, 256, 0, stream>>>(enc, xall);

    dim3 gru_grid(R_ / 64, B_ / 128, 1);       // 16 x 32 = 512 blocks
    dim3 fc_grid(4, B_ / 64, 1);               // 256 blocks
    const int binp_blocks = (B_ * IP_ + 255) / 256;
    const int fcf_blocks  = (B_ * IP_ + 255) / 256;   // fused finish covers 96 cols

    int phase = 0;

    // ---------------- encoder: 49 steps ----------------
    for (int t = 0; t < ENC_STEPS; t++) {
        u16* cur = sbuf[phase];
        u16* nxt = sbuf[phase ^ 1];
        gru_step_kernel<IP2_><<<gru_grid, 256, 0, stream>>>(
            xall + (size_t)t * B_ * IP2_, IP2_, Wi1pb,
            cur, K2_, Wh1b, bi1, bh1, s1f, nxt);
        gru_step_kernel<R_><<<gru_grid, 256, 0, stream>>>(
            nxt, K2_, Wi2b,
            cur + R_, K2_, Wh2b, bi2, bh2, s2f, nxt + R_);
        phase ^= 1;
    }

    // ---------------- decoder: 25 steps ----------------
    // initial input from dec[:, 0, :]
    build_inp_kernel<<<binp_blocks, 256, 0, stream>>>(dec, TGT_ * I_, dec, 0, xpad2);
    for (int t = 0; t < TGT_; t++) {
        const float* prev;
        int pstride;
        if (t == 0) { prev = dec;                 pstride = TGT_ * I_; }
        else        { prev = out + (t - 1) * H_;  pstride = TGT_ * H_; }
        u16* cur = sbuf[phase];
        u16* nxt = sbuf[phase ^ 1];
        gru_step_kernel<IP2_><<<gru_grid, 256, 0, stream>>>(
            xpad2, IP2_, Wi1pb,
            cur, K2_, Wh1b, bi1, bh1, s1f, nxt);
        gru_step_kernel<R_><<<gru_grid, 256, 0, stream>>>(
            nxt, K2_, Wi2b,
            cur + R_, K2_, Wh2b, bi2, bh2, s2f, nxt + R_);
        fc_part_kernel<<<fc_grid, 256, 0, stream>>>(nxt, Wfcb, cfcp);
        // fused: writes out[:, t, :] AND xpad2 for step t+1 (skip xpad on last step)
        fc_finish_kernel<<<fcf_blocks, 256, 0, stream>>>(
            cfcp, prev, pstride, bfc, out, t, dec, xpad2, (t < TGT_ - 1) ? 1 : 0);
        phase ^= 1;
    }
}

// Round 4
// 7432.091 us; speedup vs baseline: 2.4817x; 2.4817x over previous
//
#include <hip/hip_runtime.h>
#include <hip/hip_bf16.h>
#include <math.h>

// ---------------- problem constants ----------------
#define B_        4096
#define ENC_STEPS 49     // SRC-1
#define TGT_      25
#define R_        1024
#define H_        67
#define I_        82
#define IP_       96     // input padded to multiple of 32
#define IP2_      192    // split-bf16 (hi|lo) doubled K
#define NG_       3072   // 3*R
#define FCN_      128    // fc output padded 67 -> 128
#define K2_       2048   // 2*R

typedef unsigned short u16;
typedef __attribute__((ext_vector_type(8))) short bf16x8_t;
typedef __attribute__((ext_vector_type(4))) float f32x4_t;

// ---------------- helpers ----------------
__device__ __forceinline__ float bf2f(u16 h) {
    union { unsigned int u; float f; } v; v.u = ((unsigned int)h) << 16; return v.f;
}
__device__ __forceinline__ u16 f2bf(float f) {
    union { unsigned int u; float f; } v; v.f = f;
    unsigned int u = v.u;
    u += 0x7fffu + ((u >> 16) & 1u);   // RNE
    return (u16)(u >> 16);
}
__device__ __forceinline__ float sigmf(float x) { return 1.f / (1.f + __expf(-x)); }
__device__ __forceinline__ float tanhfast(float x) { return 1.f - 2.f / (__expf(2.f * x) + 1.f); }

// async global->LDS, 16B per lane. LDS dest must be wave-uniform base + lane*16,
// which our chunk mappings guarantee (lane-contiguous linear dest).
__device__ __forceinline__ void g2l16(const u16* g, u16* l) {
    __builtin_amdgcn_global_load_lds(
        (const __attribute__((address_space(1))) unsigned int*)(const void*)g,
        (__attribute__((address_space(3))) unsigned int*)(void*)l,
        16, 0, 0);
}

// ---------------- weight prep ----------------
__global__ void cast_bf16_kernel(const float* __restrict__ s, u16* __restrict__ d, int n) {
    int i = blockIdx.x * 256 + threadIdx.x;
    if (i < n) d[i] = f2bf(s[i]);
}
// Wi1 [3072,82] -> [3072,192] bf16: cols 0..95 padded Wi1, cols 96..191 duplicate (hi|lo split)
__global__ void pad_wi1_dup_kernel(const float* __restrict__ s, u16* __restrict__ d) {
    int i = blockIdx.x * 256 + threadIdx.x;
    if (i >= NG_ * IP2_) return;
    int r = i / IP2_, c = i % IP2_;
    int cc = (c < IP_) ? c : c - IP_;
    d[i] = (cc < I_) ? f2bf(s[r * I_ + cc]) : (u16)0;
}
// Wfc [67,2048] -> [128,2048] bf16, zero-padded N rows
__global__ void pad_wfc_kernel(const float* __restrict__ s, u16* __restrict__ d) {
    int i = blockIdx.x * 256 + threadIdx.x;
    if (i >= FCN_ * K2_) return;
    int r = i / K2_, c = i % K2_;
    d[i] = (r < H_) ? f2bf(s[r * K2_ + c]) : (u16)0;
}

// all encoder inputs -> xall bf16 [ENC][B][192] (hi|lo split), one launch
__global__ void pad_all_x_kernel(const float* __restrict__ enc, u16* __restrict__ xall) {
    int i = blockIdx.x * 256 + threadIdx.x;
    if (i >= B_ * ENC_STEPS * IP_) return;
    int c = i % IP_;
    int t = (i / IP_) % ENC_STEPS;
    int b = i / (IP_ * ENC_STEPS);
    float v = (c < I_) ? enc[((size_t)b * ENC_STEPS + t) * I_ + c] : 0.f;
    u16 hi = f2bf(v);
    u16 lo = f2bf(v - bf2f(hi));
    size_t base = ((size_t)t * B_ + b) * IP2_;
    xall[base + c]       = hi;
    xall[base + IP_ + c] = lo;
}

// decoder inp for t==0 (later steps are fused into fc_finish)
__global__ void build_inp_kernel(const float* __restrict__ prev, int pstride,
                                 const float* __restrict__ dec, int t,
                                 u16* __restrict__ xpad) {
    int i = blockIdx.x * 256 + threadIdx.x;
    if (i >= B_ * IP_) return;
    int b = i / IP_, c = i % IP_;
    float v = 0.f;
    if (c < H_)      v = prev[(size_t)b * pstride + c];
    else if (c < I_) v = dec[((size_t)b * TGT_ + t) * I_ + c];
    u16 hi = f2bf(v);
    u16 lo = f2bf(v - bf2f(hi));
    xpad[(size_t)b * IP2_ + c]       = hi;
    xpad[(size_t)b * IP2_ + IP_ + c] = lo;
}

// ---------------- fused GRU step (one layer) ----------------
// Tile: 128 batch rows x 64 R-cols x 3 gates; 4 waves (2M x 2N).
// BK=64: each barrier-step stages A[128x64] + W[192x64] (40 KB LDS, single
// buffer) and runs TWO K=32 MFMA sub-steps. Halves the number of
// barrier/drain cycles vs BK=32 (the measured ~2100-cyc fixed per-step cost).
// LDS rows are 128 B -> XOR swizzle pos^=(row&7) on BOTH the global source
// chunk (linear LDS dest, rule-21) and the ds_read offset; every 8-lane phase
// of ds_read_b128 then covers all 32 banks.
template<int KX>
__global__ __launch_bounds__(256, 2) void gru_step_kernel(
    const u16* __restrict__ Ax, int ldax,       // [B, ldax] bf16 input
    const u16* __restrict__ Wx,                 // [3R, KX] bf16
    const u16* __restrict__ Ah, int ldah,       // [B, ldah] bf16 state (cur)
    const u16* __restrict__ Wh,                 // [3R, 1024] bf16
    const float* __restrict__ bi, const float* __restrict__ bh,
    float* __restrict__ hf,                     // [B, R] fp32 state, in/out (in-place per-tile)
    u16* __restrict__ hout)                     // bf16 state out (nxt buffer), row stride K2_
{
    __shared__ __align__(16) u16 As[128 * 64];       // 16 KB
    __shared__ __align__(16) u16 Ws[3 * 64 * 64];    // 24 KB

    const int tid  = threadIdx.x;
    const int lane = tid & 63, wave = tid >> 6;
    const int wm = wave >> 1, wn = wave & 1;          // 2x2 waves: WM=64, WN=32
    const int mbase = blockIdx.y * 128;
    const int nbase = blockIdx.x * 64;
    const int lr = lane & 15;
    const int swkey = lr & 7;                         // row&7 == lr&7 (row bases are x16)

    constexpr int NX = KX / 64;          // x-pass BK64 steps (3 or 16)
    constexpr int NH = R_ / 64;          // h-pass BK64 steps (16)

    f32x4_t acc_r[4][2], acc_z[4][2], acc_xn[4][2], acc_hn[4][2];
#pragma unroll
    for (int i = 0; i < 4; i++)
#pragma unroll
        for (int j = 0; j < 2; j++) {
            acc_r[i][j]  = (f32x4_t){0,0,0,0};
            acc_z[i][j]  = (f32x4_t){0,0,0,0};
            acc_xn[i][j] = (f32x4_t){0,0,0,0};
            acc_hn[i][j] = (f32x4_t){0,0,0,0};
        }

    // stage one BK=64 tile: A 1024 chunks (4/thread), W 1536 chunks (6/thread)
    auto stage = [&](const u16* A, int lda, const u16* W, int ldw, int k0) {
#pragma unroll
        for (int p = 0; p < 4; p++) {
            int g = tid + p * 256;                   // 1024 = 128 rows * 8 chunks
            int row = g >> 3;
            int ch  = (g & 7) ^ (row & 7);           // pre-swizzled source chunk
            g2l16(A + (size_t)(mbase + row) * lda + k0 + ch * 8, As + g * 8);
        }
#pragma unroll
        for (int p = 0; p < 6; p++) {
            int q = tid + p * 256;                   // 1536 = 192 rows * 8 chunks
            int row = q >> 3;                        // gate*64 + rg
            int gate = row >> 6, rg = row & 63;
            int cw = (q & 7) ^ (row & 7);
            g2l16(W + ((size_t)gate * R_ + nbase + rg) * ldw + k0 + cw * 8, Ws + q * 8);
        }
    };

    // compute both K32 sub-steps of the staged BK64 tile
    auto compute = [&](bool xpass) {
#pragma unroll
        for (int kk = 0; kk < 2; kk++) {
            const int pos = ((kk * 4 + (lane >> 4)) ^ swkey) * 8;   // swizzled chunk offset
            bf16x8_t a_f[4], w_r[2], w_z[2], w_n[2];
#pragma unroll
            for (int i = 0; i < 4; i++)
                a_f[i] = *(const bf16x8_t*)(As + (wm * 64 + i * 16 + lr) * 64 + pos);
#pragma unroll
            for (int j = 0; j < 2; j++) {
                int c = wn * 32 + j * 16 + lr;
                w_r[j] = *(const bf16x8_t*)(Ws + c * 64 + pos);
                w_z[j] = *(const bf16x8_t*)(Ws + (64 + c) * 64 + pos);
                w_n[j] = *(const bf16x8_t*)(Ws + (128 + c) * 64 + pos);
            }
            __builtin_amdgcn_s_setprio(1);
#pragma unroll
            for (int i = 0; i < 4; i++)
#pragma unroll
                for (int j = 0; j < 2; j++) {
                    acc_r[i][j] = __builtin_amdgcn_mfma_f32_16x16x32_bf16(a_f[i], w_r[j], acc_r[i][j], 0, 0, 0);
                    acc_z[i][j] = __builtin_amdgcn_mfma_f32_16x16x32_bf16(a_f[i], w_z[j], acc_z[i][j], 0, 0, 0);
                }
            if (xpass) {
#pragma unroll
                for (int i = 0; i < 4; i++)
#pragma unroll
                    for (int j = 0; j < 2; j++)
                        acc_xn[i][j] = __builtin_amdgcn_mfma_f32_16x16x32_bf16(a_f[i], w_n[j], acc_xn[i][j], 0, 0, 0);
            } else {
#pragma unroll
                for (int i = 0; i < 4; i++)
#pragma unroll
                    for (int j = 0; j < 2; j++)
                        acc_hn[i][j] = __builtin_amdgcn_mfma_f32_16x16x32_bf16(a_f[i], w_n[j], acc_hn[i][j], 0, 0, 0);
            }
            __builtin_amdgcn_s_setprio(0);
        }
    };

    // ---- pass 1: x @ Wx^T ----
    for (int s = 0; s < NX; s++) {
        __syncthreads();
        stage(Ax, ldax, Wx, KX, s * 64);
        __syncthreads();
        compute(true);
    }
    // ---- pass 2: h_old @ Wh^T ----
    for (int s = 0; s < NH; s++) {
        __syncthreads();
        stage(Ah, ldah, Wh, R_, s * 64);
        __syncthreads();
        compute(false);
    }

    // ---- epilogue: gates + state update ----
    // C/D layout: col = lane&15, row = (lane>>4)*4 + reg   [HW-verified]
    const int rr2 = (lane >> 4) * 4;
#pragma unroll
    for (int j = 0; j < 2; j++) {
        const int col = nbase + wn * 32 + j * 16 + lr;
        const float b_ir = bi[col],          b_hr = bh[col];
        const float b_iz = bi[R_ + col],     b_hz = bh[R_ + col];
        const float b_in = bi[2 * R_ + col], b_hn = bh[2 * R_ + col];
#pragma unroll
        for (int i = 0; i < 4; i++) {
#pragma unroll
            for (int r = 0; r < 4; r++) {
                const int row = mbase + wm * 64 + i * 16 + rr2 + r;
                const float hold = hf[(size_t)row * R_ + col];
                const float rv = sigmf(acc_r[i][j][r] + b_ir + b_hr);
                const float zv = sigmf(acc_z[i][j][r] + b_iz + b_hz);
                const float nv = tanhfast(acc_xn[i][j][r] + b_in + rv * (acc_hn[i][j][r] + b_hn));
                const float hn = (1.f - zv) * nv + zv * hold;
                hf[(size_t)row * R_ + col] = hn;
                hout[(size_t)row * K2_ + col] = f2bf(hn);
            }
        }
    }
}

// ---------------- FC: 4-way K-split partial GEMM ----------------
// part[kc][B][128] = s12[:, kc*512:(kc+1)*512] @ Wfc[:, same]^T
__global__ __launch_bounds__(256) void fc_part_kernel(
    const u16* __restrict__ A, const u16* __restrict__ W, float* __restrict__ part) {
    __shared__ __align__(16) u16 As[64 * 32];     // 4 KB
    __shared__ __align__(16) u16 Bs[128 * 32];    // 8 KB
    const int tid  = threadIdx.x;
    const int lane = tid & 63, wave = tid >> 6;
    const int wm = wave >> 1, wn = wave & 1;      // WM=32, WN=64
    const int mbase = blockIdx.y * 64;
    const int kbase = blockIdx.x * 512;
    const int lr = lane & 15;
    const int sw = (((lane >> 4) ^ ((lr >> 1) & 3)) * 8);

    f32x4_t acc[2][4];
#pragma unroll
    for (int i = 0; i < 2; i++)
#pragma unroll
        for (int j = 0; j < 4; j++) acc[i][j] = (f32x4_t){0, 0, 0, 0};

    for (int k0 = 0; k0 < 512; k0 += 32) {
        __syncthreads();
        {
            int g = tid;                           // 256 chunks = 64 rows * 4
            int row = g >> 2;
            int ch  = (g & 3) ^ ((row >> 1) & 3);
            g2l16(A + (size_t)(mbase + row) * K2_ + kbase + k0 + ch * 8, As + g * 8);
        }
#pragma unroll
        for (int p = 0; p < 2; p++) {
            int q = tid + p * 256;                 // 512 chunks = 128 rows * 4
            int row = q >> 2;
            int cw  = (q & 3) ^ ((row >> 1) & 3);
            g2l16(W + (size_t)row * K2_ + kbase + k0 + cw * 8, Bs + q * 8);
        }
        __syncthreads();
        bf16x8_t a_f[2], b_f[4];
#pragma unroll
        for (int i = 0; i < 2; i++)
            a_f[i] = *(const bf16x8_t*)(As + (wm * 32 + i * 16 + lr) * 32 + sw);
#pragma unroll
        for (int j = 0; j < 4; j++)
            b_f[j] = *(const bf16x8_t*)(Bs + (wn * 64 + j * 16 + lr) * 32 + sw);
#pragma unroll
        for (int i = 0; i < 2; i++)
#pragma unroll
            for (int j = 0; j < 4; j++)
                acc[i][j] = __builtin_amdgcn_mfma_f32_16x16x32_bf16(a_f[i], b_f[j], acc[i][j], 0, 0, 0);
    }
    const int rr2 = (lane >> 4) * 4;
#pragma unroll
    for (int i = 0; i < 2; i++)
#pragma unroll
        for (int r = 0; r < 4; r++) {
            int row = mbase + wm * 32 + i * 16 + rr2 + r;
#pragma unroll
            for (int j = 0; j < 4; j++) {
                int col = wn * 64 + j * 16 + lr;
                part[((size_t)blockIdx.x * B_ + row) * FCN_ + col] = acc[i][j][r];
            }
        }
}

// out[:, t, :] = prev + sum(4 partials)[:, :67] + bfc  (deterministic reduce)
// FUSED: also builds xpad2 (hi|lo bf16) for decoder step t+1 when write_x != 0.
__global__ void fc_finish_kernel(const float* __restrict__ part, const float* __restrict__ prev,
                                 int pstride, const float* __restrict__ bfc,
                                 float* __restrict__ out, int t,
                                 const float* __restrict__ dec, u16* __restrict__ xpad,
                                 int write_x) {
    int i = blockIdx.x * 256 + threadIdx.x;
    if (i >= B_ * IP_) return;
    int b = i / IP_, c = i % IP_;
    float v = 0.f;
    if (c < H_) {
        size_t idx = (size_t)b * FCN_ + c;
        const size_t S = (size_t)B_ * FCN_;
        float s = (part[idx] + part[S + idx]) + (part[2 * S + idx] + part[3 * S + idx]);
        v = prev[(size_t)b * pstride + c] + s + bfc[c];
        out[((size_t)b * TGT_ + t) * H_ + c] = v;
    } else if (c < I_ && write_x) {
        v = dec[((size_t)b * TGT_ + (t + 1)) * I_ + c];   // next step's action channels
    }
    if (write_x) {
        u16 hi = f2bf(v);
        u16 lo = f2bf(v - bf2f(hi));
        xpad[(size_t)b * IP2_ + c]       = hi;
        xpad[(size_t)b * IP2_ + IP_ + c] = lo;
    }
}

// ---------------- host launcher ----------------
extern "C" void kernel_launch(void* const* d_in, const int* in_sizes, int n_in,
                              void* d_out, int out_size, void* d_ws, size_t ws_size,
                              hipStream_t stream) {
    (void)in_sizes; (void)n_in; (void)out_size; (void)ws_size;
    const float* enc = (const float*)d_in[0];
    const float* dec = (const float*)d_in[1];
    const float* Wi1 = (const float*)d_in[2];
    const float* Wh1 = (const float*)d_in[3];
    const float* bi1 = (const float*)d_in[4];
    const float* bh1 = (const float*)d_in[5];
    const float* Wi2 = (const float*)d_in[6];
    const float* Wh2 = (const float*)d_in[7];
    const float* bi2 = (const float*)d_in[8];
    const float* bh2 = (const float*)d_in[9];
    const float* Wfc = (const float*)d_in[10];
    const float* bfc = (const float*)d_in[11];
    float* out = (float*)d_out;

    char* ws = (char*)d_ws;
    size_t off = 0;
    auto alloc = [&](size_t bytes) -> char* {
        char* p = ws + off;
        off += (bytes + 255) & ~(size_t)255;
        return p;
    };
    u16* Wh1b  = (u16*)alloc((size_t)NG_ * R_ * 2);
    u16* Wi2b  = (u16*)alloc((size_t)NG_ * R_ * 2);
    u16* Wh2b  = (u16*)alloc((size_t)NG_ * R_ * 2);
    u16* Wi1pb = (u16*)alloc((size_t)NG_ * IP2_ * 2);
    u16* Wfcb  = (u16*)alloc((size_t)FCN_ * K2_ * 2);
    // contiguous zero-init group: sbuf0, s1f, s2f
    u16* sbuf0 = (u16*)alloc((size_t)B_ * K2_ * 2);
    float* s1f = (float*)alloc((size_t)B_ * R_ * 4);
    float* s2f = (float*)alloc((size_t)B_ * R_ * 4);
    u16* sbuf1 = (u16*)alloc((size_t)B_ * K2_ * 2);
    u16* xall  = (u16*)alloc((size_t)ENC_STEPS * B_ * IP2_ * 2);
    u16* xpad2 = (u16*)alloc((size_t)B_ * IP2_ * 2);
    float* cfcp = (float*)alloc((size_t)4 * B_ * FCN_ * 4);
    u16* sbuf[2] = { sbuf0, sbuf1 };

    hipMemsetAsync(sbuf0, 0,
                   (size_t)B_ * K2_ * 2 + 2 * (size_t)B_ * R_ * 4, stream);

    // weight prep (rerun every call: ws re-poisoned)
    cast_bf16_kernel<<<(NG_ * R_ + 255) / 256, 256, 0, stream>>>(Wh1, Wh1b, NG_ * R_);
    cast_bf16_kernel<<<(NG_ * R_ + 255) / 256, 256, 0, stream>>>(Wi2, Wi2b, NG_ * R_);
    cast_bf16_kernel<<<(NG_ * R_ + 255) / 256, 256, 0, stream>>>(Wh2, Wh2b, NG_ * R_);
    pad_wi1_dup_kernel<<<(NG_ * IP2_ + 255) / 256, 256, 0, stream>>>(Wi1, Wi1pb);
    pad_wfc_kernel<<<(FCN_ * K2_ + 255) / 256, 256, 0, stream>>>(Wfc, Wfcb);
    pad_all_x_kernel<<<(B_ * ENC_STEPS * IP_ + 255) / 256, 256, 0, stream>>>(enc, xall);

    dim3 gru_grid(R_ / 64, B_ / 128, 1);       // 16 x 32 = 512 blocks
    dim3 fc_grid(4, B_ / 64, 1);               // 256 blocks
    const int binp_blocks = (B_ * IP_ + 255) / 256;
    const int fcf_blocks  = (B_ * IP_ + 255) / 256;   // fused finish covers 96 cols

    int phase = 0;

    // ---------------- encoder: 49 steps ----------------
    for (int t = 0; t < ENC_STEPS; t++) {
        u16* cur = sbuf[phase];
        u16* nxt = sbuf[phase ^ 1];
        gru_step_kernel<IP2_><<<gru_grid, 256, 0, stream>>>(
            xall + (size_t)t * B_ * IP2_, IP2_, Wi1pb,
            cur, K2_, Wh1b, bi1, bh1, s1f, nxt);
        gru_step_kernel<R_><<<gru_grid, 256, 0, stream>>>(
            nxt, K2_, Wi2b,
            cur + R_, K2_, Wh2b, bi2, bh2, s2f, nxt + R_);
        phase ^= 1;
    }

    // ---------------- decoder: 25 steps ----------------
    // initial input from dec[:, 0, :]
    build_inp_kernel<<<binp_blocks, 256, 0, stream>>>(dec, TGT_ * I_, dec, 0, xpad2);
    for (int t = 0; t < TGT_; t++) {
        const float* prev;
        int pstride;
        if (t == 0) { prev = dec;                 pstride = TGT_ * I_; }
        else        { prev = out + (t - 1) * H_;  pstride = TGT_ * H_; }
        u16* cur = sbuf[phase];
        u16* nxt = sbuf[phase ^ 1];
        gru_step_kernel<IP2_><<<gru_grid, 256, 0, stream>>>(
            xpad2, IP2_, Wi1pb,
            cur, K2_, Wh1b, bi1, bh1, s1f, nxt);
        gru_step_kernel<R_><<<gru_grid, 256, 0, stream>>>(
            nxt, K2_, Wi2b,
            cur + R_, K2_, Wh2b, bi2, bh2, s2f, nxt + R_);
        fc_part_kernel<<<fc_grid, 256, 0, stream>>>(nxt, Wfcb, cfcp);
        // fused: writes out[:, t, :] AND xpad2 for step t+1 (skip xpad on last step)
        fc_finish_kernel<<<fcf_blocks, 256, 0, stream>>>(
            cfcp, prev, pstride, bfc, out, t, dec, xpad2, (t < TGT_ - 1) ? 1 : 0);
        phase ^= 1;
    }
}